// Round 6
// baseline (488.062 us; speedup 1.0000x reference)
//
#include <hip/hip_runtime.h>

// Problem constants
#define NV 65536     // flattened vectors (64*32*32)
#define KN 1024      // codebook size
#define DD 256       // embedding dim
#define DECAY_F 0.99f
#define OMD_F (1.0f - 0.99f)
#define EPS_F 1e-5f

typedef __attribute__((ext_vector_type(8))) short short8;
typedef __attribute__((ext_vector_type(16))) float f32x16;

// ---------------------------------------------------------------------------
// bf16 split helpers (RTNE)
// ---------------------------------------------------------------------------
__device__ __forceinline__ void bf16_split(float v, short& hi, short& lo) {
  unsigned u = __float_as_uint(v);
  unsigned hr = (u + 0x7FFFu + ((u >> 16) & 1u)) >> 16;
  float hf = __uint_as_float(hr << 16);
  float rem = v - hf;
  unsigned u2 = __float_as_uint(rem);
  unsigned lr = (u2 + 0x7FFFu + ((u2 >> 16) & 1u)) >> 16;
  hi = (short)hr;
  lo = (short)lr;
}

// ---------------------------------------------------------------------------
// Kernel 0 (FUSED): split_x (blocks 0..8191) + prep_e (8192..8223) +
// esq (8224..8479) + ws-zeroing (8480..8737, replaces hipMemsetAsync).
// ---------------------------------------------------------------------------
__global__ __launch_bounds__(256) void prep_all(
    const float* __restrict__ x, const float* __restrict__ emb,
    short* __restrict__ xhi, short* __restrict__ xlo,
    short* __restrict__ eT, float* __restrict__ eSq,
    float* __restrict__ zeroBase) {
  const int b = blockIdx.x;
  if (b < 8192) {
    // ---- split_x: x -> xhi/xlo bf16 arrays (same [N][D] layout) ----
    const int i = (b * 256 + threadIdx.x) * 8;
    float v[8];
    *(float4*)(v + 0) = *(const float4*)(x + i);
    *(float4*)(v + 4) = *(const float4*)(x + i + 4);
    short8 h, l;
    #pragma unroll
    for (int j = 0; j < 8; j++) {
      short hh, ll;
      bf16_split(v[j], hh, ll);
      h[j] = hh; l[j] = ll;
    }
    *(short8*)(xhi + i) = h;
    *(short8*)(xlo + i) = l;
  } else if (b < 8224) {
    // ---- prep_e: e -> MFMA tiled layout.
    // 32 tiles (cc 0..3, dc 0..7), each 16384 shorts:
    //   [h(2)][db(4)][code(256)][8]  global code = cc*256+code, d=dc*32+db*8+j
    const int bb = b - 8192;  // 0..31 = cc*8 + dc
    const int cc = bb >> 3, dc = bb & 7;
    const int c = threadIdx.x;  // code within chunk, 0..255
    const float* src = emb + (cc * 256 + c) * 256 + dc * 32;
    short* tile = eT + bb * 16384;
    #pragma unroll
    for (int db = 0; db < 4; db++) {
      float v[8];
      *(float4*)(v + 0) = *(const float4*)(src + db * 8);
      *(float4*)(v + 4) = *(const float4*)(src + db * 8 + 4);
      short8 h, l;
      #pragma unroll
      for (int j = 0; j < 8; j++) {
        short hh, ll;
        bf16_split(v[j], hh, ll);
        h[j] = hh; l[j] = ll;
      }
      *(short8*)(tile + ((0 * 4 + db) * 256 + c) * 8) = h;
      *(short8*)(tile + ((1 * 4 + db) * 256 + c) * 8) = l;
    }
  } else if (b < 8480) {
    // ---- esq: eSq[k] = ||embedding[k]||^2 (fp32). One wave per row. ----
    const int lane = threadIdx.x & 63;
    const int row = (b - 8224) * 4 + (threadIdx.x >> 6);
    const float4 v = *(const float4*)(emb + row * DD + lane * 4);
    float s = v.x * v.x + v.y * v.y + v.z * v.z + v.w * v.w;
    #pragma unroll
    for (int off = 32; off > 0; off >>= 1) s += __shfl_down(s, off, 64);
    if (lane == 0) eSq[row] = s;
  } else {
    // ---- zero sseSlots(256) + cntI(1024) + dw(262144) = 263424 floats ----
    const int i = ((b - 8480) * 256 + threadIdx.x) * 4;
    if (i < 263424)
      *(float4*)(zeroBase + i) = make_float4(0.0f, 0.0f, 0.0f, 0.0f);
  }
}

// ---------------------------------------------------------------------------
// Kernel 2: MFMA distance + exact best-2 candidates.
// R6: BARRIER-FREE STREAMING. No LDS staging of eT: each wave reads its
// B-fragments (identical bytes/layout to what LDS held) directly from
// global eT into registers. eT is 1 MB, L2-resident, replicated per-XCD;
// per-CU L2 BW (~135 B/cy) > MFMA-pipe demand. acc pins us at 1 wave/SIMD
// (2x128 AGPR), so TLP can't hide barrier drains -- therefore NO barriers:
// zero __syncthreads in the kernel. The fold buffer is wave-local LDS
// (cross-lane within one wave; compiler orders ds ops via lgkmcnt).
// Per ks-phase: 16 global_load_dwordx4 (B) covered by 48 MFMAs of issue.
// ---------------------------------------------------------------------------
__global__ __launch_bounds__(256, 1) void argmin_mfma(
    const short* __restrict__ xhi, const short* __restrict__ xlo,
    const short* __restrict__ eT, const float* __restrict__ eSq,
    int2* __restrict__ cand) {
  __shared__ __align__(16) float2 dbAll[4 * 64 * 33];  // per-wave fold bufs

  const int tid = threadIdx.x;
  const int lane = tid & 63;
  const int wid = tid >> 6;
  const int l31 = lane & 31;
  const int lh = lane >> 5;
  const int qBase = blockIdx.x * 256 + wid * 64;  // 64 queries per wave

  float2* dbW = dbAll + wid * (64 * 33);

  float b1d[2] = {3.4e38f, 3.4e38f}, b2d[2] = {3.4e38f, 3.4e38f};
  int b1k[2] = {0, 0}, b2k[2] = {1, 1};

  const long qRow0 = (long)(qBase + l31) * DD;
  const long qRow1 = qRow0 + 32 * DD;

  for (int cc = 0; cc < 4; cc++) {
    f32x16 acc0[8], acc1[8];
    #pragma unroll
    for (int ct = 0; ct < 8; ct++)
      #pragma unroll
      for (int i = 0; i < 16; i++) { acc0[ct][i] = 0.0f; acc1[ct][i] = 0.0f; }

    float es2[8];
    #pragma unroll
    for (int ct = 0; ct < 8; ct++) es2[ct] = eSq[cc * 256 + ct * 32 + l31];

    for (int dc = 0; dc < 8; dc++) {
      const short* tile = eT + (cc * 8 + dc) * 16384;

      // A-fragments for both m-tiles, both ks (8 x 16B global loads)
      short8 a0h[2], a0l[2], a1h[2], a1l[2];
      #pragma unroll
      for (int ks = 0; ks < 2; ks++) {
        const int d = dc * 32 + ks * 16 + lh * 8;
        a0h[ks] = *(const short8*)(xhi + qRow0 + d);
        a0l[ks] = *(const short8*)(xlo + qRow0 + d);
        a1h[ks] = *(const short8*)(xhi + qRow1 + d);
        a1l[ks] = *(const short8*)(xlo + qRow1 + d);
      }

      #pragma unroll
      for (int ks = 0; ks < 2; ks++) {
        const int db = ks * 2 + lh;
        // 16 B-fragments straight from L2 into registers
        short8 bh[8], bl[8];
        #pragma unroll
        for (int ct = 0; ct < 8; ct++) {
          const int cL = ct * 32 + l31;
          bh[ct] = *(const short8*)(tile + ((0 * 4 + db) * 256 + cL) * 8);
          bl[ct] = *(const short8*)(tile + ((1 * 4 + db) * 256 + cL) * 8);
        }
        // 48 MFMAs: each B-pair feeds 6 (2 m-tiles x 3-MFMA hi/lo product)
        #pragma unroll
        for (int ct = 0; ct < 8; ct++) {
          acc0[ct] = __builtin_amdgcn_mfma_f32_32x32x16_bf16(a0h[ks], bh[ct], acc0[ct], 0, 0, 0);
          acc0[ct] = __builtin_amdgcn_mfma_f32_32x32x16_bf16(a0h[ks], bl[ct], acc0[ct], 0, 0, 0);
          acc0[ct] = __builtin_amdgcn_mfma_f32_32x32x16_bf16(a0l[ks], bh[ct], acc0[ct], 0, 0, 0);
          acc1[ct] = __builtin_amdgcn_mfma_f32_32x32x16_bf16(a1h[ks], bh[ct], acc1[ct], 0, 0, 0);
          acc1[ct] = __builtin_amdgcn_mfma_f32_32x32x16_bf16(a1h[ks], bl[ct], acc1[ct], 0, 0, 0);
          acc1[ct] = __builtin_amdgcn_mfma_f32_32x32x16_bf16(a1l[ks], bh[ct], acc1[ct], 0, 0, 0);
        }
      }
    }

    // fold phase: wave-local LDS transpose, two passes (m=0,1), NO barriers
    // (dbW is private to this wave; compiler orders ds write->read via
    // lgkmcnt since it cannot prove non-aliasing).
    #pragma unroll
    for (int m = 0; m < 2; m++) {
      #pragma unroll
      for (int r = 0; r < 16; r++) {
        const int row = (r & 3) + 8 * (r >> 2) + 4 * lh;  // query row 0..31
        float cb1 = 3.4e38f, cb2 = 3.4e38f;
        int ck1 = 0, ck2 = 0;
        #pragma unroll
        for (int ct = 0; ct < 8; ct++) {
          const float dd = es2[ct] - 2.0f * (m ? acc1[ct][r] : acc0[ct][r]);
          const int k = cc * 256 + ct * 32 + l31;
          if (dd < cb1) { cb2 = cb1; ck2 = ck1; cb1 = dd; ck1 = k; }
          else if (dd < cb2) { cb2 = dd; ck2 = k; }
        }
        dbW[(l31 * 2 + 0) * 33 + row] = make_float2(cb1, __int_as_float(ck1));
        dbW[(l31 * 2 + 1) * 33 + row] = make_float2(cb2, __int_as_float(ck2));
      }
      // lane (l31, lh) folds candidates lh*32..lh*32+31 for query m*32+l31
      #pragma unroll
      for (int i = 0; i < 32; i++) {
        const float2 c = dbW[(lh * 32 + i) * 33 + l31];
        const float dd = c.x;
        const int k = __float_as_int(c.y);
        if (dd < b1d[m]) { b2d[m] = b1d[m]; b2k[m] = b1k[m]; b1d[m] = dd; b1k[m] = k; }
        else if (dd < b2d[m]) { b2d[m] = dd; b2k[m] = k; }
      }
    }
  }

  // merge lane pairs (l, l+32) per m-tile: exact best2 of union, k-tiebreak
  #pragma unroll
  for (int m = 0; m < 2; m++) {
    const float p1d = __shfl_xor(b1d[m], 32, 64);
    const int p1k = __shfl_xor(b1k[m], 32, 64);
    const float p2d = __shfl_xor(b2d[m], 32, 64);
    const int p2k = __shfl_xor(b2k[m], 32, 64);
    if ((p1d < b1d[m]) || (p1d == b1d[m] && p1k < b1k[m])) {
      b2d[m] = b1d[m]; b2k[m] = b1k[m]; b1d[m] = p1d; b1k[m] = p1k;
    } else if ((p1d < b2d[m]) || (p1d == b2d[m] && p1k < b2k[m])) {
      b2d[m] = p1d; b2k[m] = p1k;
    }
    if ((p2d < b1d[m]) || (p2d == b1d[m] && p2k < b1k[m])) {
      b2d[m] = b1d[m]; b2k[m] = b1k[m]; b1d[m] = p2d; b1k[m] = p2k;
    } else if ((p2d < b2d[m]) || (p2d == b2d[m] && p2k < b2k[m])) {
      b2d[m] = p2d; b2k[m] = p2k;
    }
    if (lh == 0) cand[qBase + m * 32 + l31] = make_int2(b1k[m], b2k[m]);
  }
}

// ---------------------------------------------------------------------------
// Kernel 3: exact fp32 rescue of the 2 candidates + gather + codes + SSE
//           + fused histogram of final indices (cntI).
// One wave per query.
// ---------------------------------------------------------------------------
__global__ __launch_bounds__(256) void gather_rescue(
    const float* __restrict__ x, const float* __restrict__ emb,
    const int2* __restrict__ cand, float* __restrict__ outQ,
    float* __restrict__ outCodes, int* __restrict__ idxFinal,
    float* __restrict__ sseSlots, int* __restrict__ cntI) {
  const int lane = threadIdx.x & 63;
  const int n = blockIdx.x * 4 + (threadIdx.x >> 6);
  const int2 kk = cand[n];

  const float4 xv = *(const float4*)(x + n * DD + lane * 4);
  const float4 e1 = *(const float4*)(emb + kk.x * DD + lane * 4);
  const float4 e2 = *(const float4*)(emb + kk.y * DD + lane * 4);

  float p1 = e1.x * (e1.x - 2.0f * xv.x) + e1.y * (e1.y - 2.0f * xv.y) +
             e1.z * (e1.z - 2.0f * xv.z) + e1.w * (e1.w - 2.0f * xv.w);
  float p2 = e2.x * (e2.x - 2.0f * xv.x) + e2.y * (e2.y - 2.0f * xv.y) +
             e2.z * (e2.z - 2.0f * xv.z) + e2.w * (e2.w - 2.0f * xv.w);
  #pragma unroll
  for (int m = 32; m > 0; m >>= 1) {
    p1 += __shfl_xor(p1, m, 64);
    p2 += __shfl_xor(p2, m, 64);
  }
  const bool pick2 = (p2 < p1) || (p2 == p1 && kk.y < kk.x);
  const int ksel = pick2 ? kk.y : kk.x;
  const float4 ev = pick2 ? e2 : e1;

  *(float4*)(outQ + n * DD + lane * 4) = ev;

  const float d0 = ev.x - xv.x, d1 = ev.y - xv.y, d2 = ev.z - xv.z,
              d3 = ev.w - xv.w;
  float s = d0 * d0 + d1 * d1 + d2 * d2 + d3 * d3;
  #pragma unroll
  for (int m = 32; m > 0; m >>= 1) s += __shfl_down(s, m, 64);
  if (lane == 0) {
    atomicAdd(&sseSlots[n & 255], s);
    atomicAdd(&cntI[ksel], 1);
    idxFinal[n] = ksel;
    outCodes[n] = (float)ksel;
  }
}

// ---------------------------------------------------------------------------
// Kernel 4a: FUSED scan + finalize1 (both single-block; one drain less).
// Scan cntI -> starts/cursor; new_cluster_size, n-sum, norm, losses.
// ---------------------------------------------------------------------------
__global__ __launch_bounds__(1024) void scan_fin(
    const int* __restrict__ cntI, const float* __restrict__ ema_cs,
    const float* __restrict__ sseSlots, int* __restrict__ starts,
    int* __restrict__ cursor, float* __restrict__ norm,
    float* __restrict__ outCS, float* __restrict__ outLoss) {
  __shared__ int si[1024];
  __shared__ float red[1024];
  const int t = threadIdx.x;
  const int v = cntI[t];
  si[t] = v;
  __syncthreads();
  #pragma unroll
  for (int off = 1; off < 1024; off <<= 1) {
    const int add = (t >= off) ? si[t - off] : 0;
    __syncthreads();
    si[t] += add;
    __syncthreads();
  }
  const int excl = si[t] - v;  // exclusive prefix = segment start
  starts[t] = excl;
  cursor[t] = excl;

  // finalize1 part
  const float ncs = DECAY_F * ema_cs[t] + OMD_F * (float)v;
  outCS[t] = ncs;
  red[t] = ncs;
  __syncthreads();
  #pragma unroll
  for (int s = 512; s > 0; s >>= 1) {
    if (t < s) red[t] += red[t + s];
    __syncthreads();
  }
  const float n = red[0];
  __syncthreads();
  norm[t] = (ncs + EPS_F) / (n + (float)KN * EPS_F) * n;

  red[t] = (t < 256) ? sseSlots[t] : 0.0f;
  __syncthreads();
  #pragma unroll
  for (int s = 512; s > 0; s >>= 1) {
    if (t < s) red[t] += red[t + s];
    __syncthreads();
  }
  if (t == 0) {
    const float mse = red[0] * (1.0f / 16777216.0f);
    outLoss[0] = 0.25f * mse;  // commitment
    outLoss[1] = mse;          // codebook
  }
}

// ---------------------------------------------------------------------------
// Kernel 4b: scatter each n into its code's segment (counting sort).
// perm[pos] packs (k << 16) | n  (k < 1024 in bits 16..25, n < 65536).
// ---------------------------------------------------------------------------
__global__ __launch_bounds__(256) void scatter_kernel(
    const int* __restrict__ idx, int* __restrict__ cursor,
    int* __restrict__ perm) {
  const int n = blockIdx.x * 256 + threadIdx.x;
  const int k = idx[n];
  const int pos = atomicAdd(&cursor[k], 1);
  perm[pos] = (k << 16) | n;
}

// ---------------------------------------------------------------------------
// Kernel 4c: BALANCED low-atomic segmented sum.
// 512 blocks x 4 waves; each wave owns 32 CONSECUTIVE sorted rows (~1.25
// code-runs avg). Rows staged 8-deep in registers, register accumulate,
// flush on code-change via 4 scalar atomicAdds/lane. No tail skew.
// dw must be zeroed beforehand.
// ---------------------------------------------------------------------------
__global__ __launch_bounds__(256) void dw_sum(const float* __restrict__ x,
                                              const int* __restrict__ perm,
                                              float* __restrict__ dw) {
  __shared__ int sp[128];
  const int tid = threadIdx.x;
  if (tid < 128) sp[tid] = perm[blockIdx.x * 128 + tid];
  __syncthreads();
  const int w = tid >> 6;
  const int l = tid & 63;
  const int* wp = sp + w * 32;

  float4 acc = make_float4(0.0f, 0.0f, 0.0f, 0.0f);
  int kcur = wp[0] >> 16;

  #pragma unroll
  for (int c = 0; c < 4; c++) {
    float4 v[8];
    int kk[8];
    #pragma unroll
    for (int j = 0; j < 8; j++) {
      const int p = wp[c * 8 + j];
      kk[j] = p >> 16;
      v[j] = *(const float4*)(x + (long)(p & 0xFFFF) * DD + l * 4);
    }
    #pragma unroll
    for (int j = 0; j < 8; j++) {
      if (kk[j] != kcur) {
        float* drow = dw + kcur * DD + l * 4;
        atomicAdd(drow + 0, acc.x);
        atomicAdd(drow + 1, acc.y);
        atomicAdd(drow + 2, acc.z);
        atomicAdd(drow + 3, acc.w);
        acc = make_float4(0.0f, 0.0f, 0.0f, 0.0f);
        kcur = kk[j];
      }
      acc.x += v[j].x; acc.y += v[j].y;
      acc.z += v[j].z; acc.w += v[j].w;
    }
  }
  {
    float* drow = dw + kcur * DD + l * 4;
    atomicAdd(drow + 0, acc.x);
    atomicAdd(drow + 1, acc.y);
    atomicAdd(drow + 2, acc.z);
    atomicAdd(drow + 3, acc.w);
  }
}

// ---------------------------------------------------------------------------
// Kernel 5: new_ema_w and new_embedding.
// ---------------------------------------------------------------------------
__global__ __launch_bounds__(256) void finalize2(
    const float* __restrict__ ema_w, const float* __restrict__ dw,
    const float* __restrict__ norm, float* __restrict__ outEmb,
    float* __restrict__ outW) {
  const int i = blockIdx.x * 256 + threadIdx.x;  // 0..262143
  const float nw = DECAY_F * ema_w[i] + OMD_F * dw[i];
  outW[i] = nw;
  outEmb[i] = nw / norm[i >> 8];
}

// ---------------------------------------------------------------------------
extern "C" void kernel_launch(void* const* d_in, const int* in_sizes, int n_in,
                              void* d_out, int out_size, void* d_ws, size_t ws_size,
                              hipStream_t stream) {
  const float* x = (const float*)d_in[0];        // [65536, 256]
  const float* emb = (const float*)d_in[1];      // [1024, 256]
  const float* ema_cs = (const float*)d_in[2];   // [1024]
  const float* ema_w = (const float*)d_in[3];    // [1024, 256]
  float* out = (float*)d_out;
  float* ws = (float*)d_ws;

  // --- workspace (float offsets) ---
  float* eSq = ws + 0;                   // 1024
  float* sseSlots = ws + 1024;           // 256   (zeroed by prep_all)
  int* cntI = (int*)(ws + 1280);         // 1024 ints (zeroed by prep_all)
  float* dw = ws + 2304;                 // 262144 (zeroed by prep_all)
  float* norm = ws + 264448;             // 1024
  int* starts = (int*)(ws + 265472);     // 1024 ints
  int* cursor = (int*)(ws + 266496);     // 1024 ints
  int* idxFinal = (int*)(ws + 267520);   // 65536 ints
  int* perm = (int*)(ws + 333056);       // 65536 ints (packed (k<<16)|n)

  // --- d_out doubles as phase-1 scratch (stream-ordered lifetimes) ---
  short* xhi = (short*)out;                     // out[0..8388608)
  short* xlo = (short*)(out + 8388608);         // out[8388608..16777216)
  short* eT = (short*)(out + 16777216);         // 524288 shorts
  int2* cand = (int2*)(out + 17039360);         // 65536 int2

  // --- final output layout (return-order flat, fp32) ---
  float* outQ = out;                    // 16777216  quantized_st
  float* outCodes = out + 16777216;     // 65536     codes (as float)
  float* outLoss = out + 16842752;      // 2         commitment, codebook
  float* outEmb = out + 16842754;       // 262144    new_embedding
  float* outCS = out + 17104898;        // 1024      new_cluster_size
  float* outW = out + 17105922;         // 262144    new_ema_w

  prep_all<<<8738, 256, 0, stream>>>(x, emb, xhi, xlo, eT, eSq, ws + 1024);
  argmin_mfma<<<NV / 256, 256, 0, stream>>>(xhi, xlo, eT, eSq, cand);
  gather_rescue<<<NV / 4, 256, 0, stream>>>(x, emb, cand, outQ, outCodes,
                                            idxFinal, sseSlots, cntI);
  scan_fin<<<1, 1024, 0, stream>>>(cntI, ema_cs, sseSlots, starts, cursor,
                                   norm, outCS, outLoss);
  scatter_kernel<<<NV / 256, 256, 0, stream>>>(idxFinal, cursor, perm);
  dw_sum<<<NV / 128, 256, 0, stream>>>(x, perm, dw);
  finalize2<<<KN * DD / 256, 256, 0, stream>>>(ema_w, dw, norm, outEmb, outW);
}

// Round 7
// 411.212 us; speedup vs baseline: 1.1869x; 1.1869x over previous
//
#include <hip/hip_runtime.h>

// Problem constants
#define NV 65536     // flattened vectors (64*32*32)
#define KN 1024      // codebook size
#define DD 256       // embedding dim
#define DECAY_F 0.99f
#define OMD_F (1.0f - 0.99f)
#define EPS_F 1e-5f

typedef __attribute__((ext_vector_type(8))) short short8;
typedef __attribute__((ext_vector_type(16))) float f32x16;

// ---------------------------------------------------------------------------
// async global->LDS 16B copy. LDS dest is wave-uniform base; HW writes
// base + lane*16. Removes the VGPR round-trip + ds_write VALU of staging.
// ---------------------------------------------------------------------------
__device__ __forceinline__ void gl_lds16(const void* g, void* l) {
  __builtin_amdgcn_global_load_lds(
      (const __attribute__((address_space(1))) unsigned int*)g,
      (__attribute__((address_space(3))) unsigned int*)l, 16, 0, 0);
}

// ---------------------------------------------------------------------------
// bf16 split helpers (RTNE)
// ---------------------------------------------------------------------------
__device__ __forceinline__ void bf16_split(float v, short& hi, short& lo) {
  unsigned u = __float_as_uint(v);
  unsigned hr = (u + 0x7FFFu + ((u >> 16) & 1u)) >> 16;
  float hf = __uint_as_float(hr << 16);
  float rem = v - hf;
  unsigned u2 = __float_as_uint(rem);
  unsigned lr = (u2 + 0x7FFFu + ((u2 >> 16) & 1u)) >> 16;
  hi = (short)hr;
  lo = (short)lr;
}

// ---------------------------------------------------------------------------
// Kernel 0 (FUSED): split_x (blocks 0..8191) + prep_e (8192..8223) +
// esq (8224..8479) + ws-zeroing (8480..8737, replaces hipMemsetAsync).
// ---------------------------------------------------------------------------
__global__ __launch_bounds__(256) void prep_all(
    const float* __restrict__ x, const float* __restrict__ emb,
    short* __restrict__ xhi, short* __restrict__ xlo,
    short* __restrict__ eT, float* __restrict__ eSq,
    float* __restrict__ zeroBase) {
  const int b = blockIdx.x;
  if (b < 8192) {
    // ---- split_x: x -> xhi/xlo bf16 arrays (same [N][D] layout) ----
    const int i = (b * 256 + threadIdx.x) * 8;
    float v[8];
    *(float4*)(v + 0) = *(const float4*)(x + i);
    *(float4*)(v + 4) = *(const float4*)(x + i + 4);
    short8 h, l;
    #pragma unroll
    for (int j = 0; j < 8; j++) {
      short hh, ll;
      bf16_split(v[j], hh, ll);
      h[j] = hh; l[j] = ll;
    }
    *(short8*)(xhi + i) = h;
    *(short8*)(xlo + i) = l;
  } else if (b < 8224) {
    // ---- prep_e: e -> MFMA tiled layout.
    // 32 tiles (cc 0..3, dc 0..7), each 16384 shorts:
    //   [h(2)][db(4)][code(256)][8]  global code = cc*256+code, d=dc*32+db*8+j
    const int bb = b - 8192;  // 0..31 = cc*8 + dc
    const int cc = bb >> 3, dc = bb & 7;
    const int c = threadIdx.x;  // code within chunk, 0..255
    const float* src = emb + (cc * 256 + c) * 256 + dc * 32;
    short* tile = eT + bb * 16384;
    #pragma unroll
    for (int db = 0; db < 4; db++) {
      float v[8];
      *(float4*)(v + 0) = *(const float4*)(src + db * 8);
      *(float4*)(v + 4) = *(const float4*)(src + db * 8 + 4);
      short8 h, l;
      #pragma unroll
      for (int j = 0; j < 8; j++) {
        short hh, ll;
        bf16_split(v[j], hh, ll);
        h[j] = hh; l[j] = ll;
      }
      *(short8*)(tile + ((0 * 4 + db) * 256 + c) * 8) = h;
      *(short8*)(tile + ((1 * 4 + db) * 256 + c) * 8) = l;
    }
  } else if (b < 8480) {
    // ---- esq: eSq[k] = ||embedding[k]||^2 (fp32). One wave per row. ----
    const int lane = threadIdx.x & 63;
    const int row = (b - 8224) * 4 + (threadIdx.x >> 6);
    const float4 v = *(const float4*)(emb + row * DD + lane * 4);
    float s = v.x * v.x + v.y * v.y + v.z * v.z + v.w * v.w;
    #pragma unroll
    for (int off = 32; off > 0; off >>= 1) s += __shfl_down(s, off, 64);
    if (lane == 0) eSq[row] = s;
  } else {
    // ---- zero sseSlots(256) + cntI(1024) + dw(262144) = 263424 floats ----
    const int i = ((b - 8480) * 256 + threadIdx.x) * 4;
    if (i < 263424)
      *(float4*)(zeroBase + i) = make_float4(0.0f, 0.0f, 0.0f, 0.0f);
  }
}

// ---------------------------------------------------------------------------
// Kernel 2: MFMA distance + exact best-2 candidates.
// R7: REVERT to the proven R1/R2 structure (best measured 131 us):
//   32 q/wave, 512 blocks (2/CU), LDS-staged eT, 2 barriers/dc-step,
//   acc[8] = 128 AGPR, ~100 VGPR -> fits (256,2) with no spill.
// Single delta vs R1: staging via gl_lds16 (no VGPR round-trip, no ds_write
// VALU) -- single-buffered, NO prefetch, so register liveness stays R1-low
// (R4's spill came from the double-buffer liveness, not gl_lds itself).
// Ledger: R4 pipeline=neutral, R5/R6 double-M=regress (reg pool), so LDS
// read-traffic is structural at 2 waves/SIMD; this only trims write cost.
// ---------------------------------------------------------------------------
__global__ __launch_bounds__(256, 2) void argmin_mfma(
    const short* __restrict__ xhi, const short* __restrict__ xlo,
    const short* __restrict__ eT, const float* __restrict__ eSq,
    int2* __restrict__ cand) {
  __shared__ __align__(16) char uS[67584];  // union: eS (32 KB) / db (66 KB)
  __shared__ float eSqS[1024];

  short* eS = (short*)uS;
  float2* dbAll = (float2*)uS;

  const int tid = threadIdx.x;
  const int lane = tid & 63;
  const int wid = tid >> 6;
  const int l31 = lane & 31;
  const int lh = lane >> 5;
  const int qBase = blockIdx.x * 128 + wid * 32;

  // stage eSq once (1024 floats)
  *(float4*)(eSqS + tid * 4) = *(const float4*)(eSq + tid * 4);
  __syncthreads();  // eSqS visible to all waves BEFORE first es2 read

  float2* dbW = dbAll + wid * (64 * 33);

  float b1d = 3.4e38f, b2d = 3.4e38f;
  int b1k = 0, b2k = 1;

  const long qRow = (long)(qBase + l31) * DD;

  const int wbase = wid * 1024;   // wave-uniform LDS sub-base (stage split)
  const int lane16 = lane * 16;   // per-lane global offset

  for (int cc = 0; cc < 4; cc++) {
    f32x16 acc[8];
    #pragma unroll
    for (int ct = 0; ct < 8; ct++)
      #pragma unroll
      for (int i = 0; i < 16; i++) acc[ct][i] = 0.0f;

    float es2[8];
    #pragma unroll
    for (int ct = 0; ct < 8; ct++) es2[ct] = eSqS[cc * 256 + ct * 32 + l31];

    for (int dc = 0; dc < 8; dc++) {
      __syncthreads();  // prior eS/db reads complete
      {
        const char* src = (const char*)(eT + (cc * 8 + dc) * 16384);
        #pragma unroll
        for (int i = 0; i < 8; i++)
          gl_lds16(src + i * 4096 + wbase + lane16, uS + i * 4096 + wbase);
      }
      __syncthreads();  // tile staged (barrier drains vmcnt incl. gl_lds)

      #pragma unroll
      for (int ks = 0; ks < 2; ks++) {
        const int d = dc * 32 + ks * 16 + lh * 8;
        const short8 ahi = *(const short8*)(xhi + qRow + d);
        const short8 alo = *(const short8*)(xlo + qRow + d);
        const int db = ks * 2 + lh;
        #pragma unroll
        for (int ct = 0; ct < 8; ct++) {
          const int cL = ct * 32 + l31;
          const short8 bhi = *(const short8*)(eS + ((0 * 4 + db) * 256 + cL) * 8);
          const short8 blo = *(const short8*)(eS + ((1 * 4 + db) * 256 + cL) * 8);
          acc[ct] = __builtin_amdgcn_mfma_f32_32x32x16_bf16(ahi, bhi, acc[ct], 0, 0, 0);
          acc[ct] = __builtin_amdgcn_mfma_f32_32x32x16_bf16(ahi, blo, acc[ct], 0, 0, 0);
          acc[ct] = __builtin_amdgcn_mfma_f32_32x32x16_bf16(alo, bhi, acc[ct], 0, 0, 0);
        }
      }
    }

    __syncthreads();  // all waves done reading eS; uS becomes fold buffer

    // per-(lane,reg): exact best2 over the 8 ct codes; transpose via LDS.
    // db layout per wave: float2 [cand(64)][query(32)+1pad]
    #pragma unroll
    for (int r = 0; r < 16; r++) {
      const int row = (r & 3) + 8 * (r >> 2) + 4 * lh;  // query row 0..31
      float cb1 = 3.4e38f, cb2 = 3.4e38f;
      int ck1 = 0, ck2 = 0;
      #pragma unroll
      for (int ct = 0; ct < 8; ct++) {
        const float dd = es2[ct] - 2.0f * acc[ct][r];
        const int k = cc * 256 + ct * 32 + l31;
        if (dd < cb1) { cb2 = cb1; ck2 = ck1; cb1 = dd; ck1 = k; }
        else if (dd < cb2) { cb2 = dd; ck2 = k; }
      }
      dbW[(l31 * 2 + 0) * 33 + row] = make_float2(cb1, __int_as_float(ck1));
      dbW[(l31 * 2 + 1) * 33 + row] = make_float2(cb2, __int_as_float(ck2));
    }
    __syncthreads();  // transpose visible (also keeps waves phase-aligned)

    // lane (l31, lh) folds candidates lh*32..lh*32+31 for query l31
    #pragma unroll
    for (int i = 0; i < 32; i++) {
      const float2 c = dbW[(lh * 32 + i) * 33 + l31];
      const float dd = c.x;
      const int k = __float_as_int(c.y);
      if (dd < b1d) { b2d = b1d; b2k = b1k; b1d = dd; b1k = k; }
      else if (dd < b2d) { b2d = dd; b2k = k; }
    }
  }

  // merge lane pairs (l, l+32): exact best2 of the union, k-tiebreak
  {
    const float p1d = __shfl_xor(b1d, 32, 64);
    const int p1k = __shfl_xor(b1k, 32, 64);
    const float p2d = __shfl_xor(b2d, 32, 64);
    const int p2k = __shfl_xor(b2k, 32, 64);
    if ((p1d < b1d) || (p1d == b1d && p1k < b1k)) {
      b2d = b1d; b2k = b1k; b1d = p1d; b1k = p1k;
    } else if ((p1d < b2d) || (p1d == b2d && p1k < b2k)) {
      b2d = p1d; b2k = p1k;
    }
    if ((p2d < b1d) || (p2d == b1d && p2k < b1k)) {
      b2d = b1d; b2k = b1k; b1d = p2d; b1k = p2k;
    } else if ((p2d < b2d) || (p2d == b2d && p2k < b2k)) {
      b2d = p2d; b2k = p2k;
    }
  }
  if (lh == 0) cand[qBase + l31] = make_int2(b1k, b2k);
}

// ---------------------------------------------------------------------------
// Kernel 3: exact fp32 rescue of the 2 candidates + gather + codes + SSE
//           + fused histogram of final indices (cntI).
// One wave per query.
// ---------------------------------------------------------------------------
__global__ __launch_bounds__(256) void gather_rescue(
    const float* __restrict__ x, const float* __restrict__ emb,
    const int2* __restrict__ cand, float* __restrict__ outQ,
    float* __restrict__ outCodes, int* __restrict__ idxFinal,
    float* __restrict__ sseSlots, int* __restrict__ cntI) {
  const int lane = threadIdx.x & 63;
  const int n = blockIdx.x * 4 + (threadIdx.x >> 6);
  const int2 kk = cand[n];

  const float4 xv = *(const float4*)(x + n * DD + lane * 4);
  const float4 e1 = *(const float4*)(emb + kk.x * DD + lane * 4);
  const float4 e2 = *(const float4*)(emb + kk.y * DD + lane * 4);

  float p1 = e1.x * (e1.x - 2.0f * xv.x) + e1.y * (e1.y - 2.0f * xv.y) +
             e1.z * (e1.z - 2.0f * xv.z) + e1.w * (e1.w - 2.0f * xv.w);
  float p2 = e2.x * (e2.x - 2.0f * xv.x) + e2.y * (e2.y - 2.0f * xv.y) +
             e2.z * (e2.z - 2.0f * xv.z) + e2.w * (e2.w - 2.0f * xv.w);
  #pragma unroll
  for (int m = 32; m > 0; m >>= 1) {
    p1 += __shfl_xor(p1, m, 64);
    p2 += __shfl_xor(p2, m, 64);
  }
  const bool pick2 = (p2 < p1) || (p2 == p1 && kk.y < kk.x);
  const int ksel = pick2 ? kk.y : kk.x;
  const float4 ev = pick2 ? e2 : e1;

  *(float4*)(outQ + n * DD + lane * 4) = ev;

  const float d0 = ev.x - xv.x, d1 = ev.y - xv.y, d2 = ev.z - xv.z,
              d3 = ev.w - xv.w;
  float s = d0 * d0 + d1 * d1 + d2 * d2 + d3 * d3;
  #pragma unroll
  for (int m = 32; m > 0; m >>= 1) s += __shfl_down(s, m, 64);
  if (lane == 0) {
    atomicAdd(&sseSlots[n & 255], s);
    atomicAdd(&cntI[ksel], 1);
    idxFinal[n] = ksel;
    outCodes[n] = (float)ksel;
  }
}

// ---------------------------------------------------------------------------
// Kernel 4a: FUSED scan + finalize1 (both single-block; one drain less).
// Scan cntI -> starts/cursor; new_cluster_size, n-sum, norm, losses.
// ---------------------------------------------------------------------------
__global__ __launch_bounds__(1024) void scan_fin(
    const int* __restrict__ cntI, const float* __restrict__ ema_cs,
    const float* __restrict__ sseSlots, int* __restrict__ starts,
    int* __restrict__ cursor, float* __restrict__ norm,
    float* __restrict__ outCS, float* __restrict__ outLoss) {
  __shared__ int si[1024];
  __shared__ float red[1024];
  const int t = threadIdx.x;
  const int v = cntI[t];
  si[t] = v;
  __syncthreads();
  #pragma unroll
  for (int off = 1; off < 1024; off <<= 1) {
    const int add = (t >= off) ? si[t - off] : 0;
    __syncthreads();
    si[t] += add;
    __syncthreads();
  }
  const int excl = si[t] - v;  // exclusive prefix = segment start
  starts[t] = excl;
  cursor[t] = excl;

  // finalize1 part
  const float ncs = DECAY_F * ema_cs[t] + OMD_F * (float)v;
  outCS[t] = ncs;
  red[t] = ncs;
  __syncthreads();
  #pragma unroll
  for (int s = 512; s > 0; s >>= 1) {
    if (t < s) red[t] += red[t + s];
    __syncthreads();
  }
  const float n = red[0];
  __syncthreads();
  norm[t] = (ncs + EPS_F) / (n + (float)KN * EPS_F) * n;

  red[t] = (t < 256) ? sseSlots[t] : 0.0f;
  __syncthreads();
  #pragma unroll
  for (int s = 512; s > 0; s >>= 1) {
    if (t < s) red[t] += red[t + s];
    __syncthreads();
  }
  if (t == 0) {
    const float mse = red[0] * (1.0f / 16777216.0f);
    outLoss[0] = 0.25f * mse;  // commitment
    outLoss[1] = mse;          // codebook
  }
}

// ---------------------------------------------------------------------------
// Kernel 4b: scatter each n into its code's segment (counting sort).
// perm[pos] packs (k << 16) | n  (k < 1024 in bits 16..25, n < 65536).
// ---------------------------------------------------------------------------
__global__ __launch_bounds__(256) void scatter_kernel(
    const int* __restrict__ idx, int* __restrict__ cursor,
    int* __restrict__ perm) {
  const int n = blockIdx.x * 256 + threadIdx.x;
  const int k = idx[n];
  const int pos = atomicAdd(&cursor[k], 1);
  perm[pos] = (k << 16) | n;
}

// ---------------------------------------------------------------------------
// Kernel 4c: BALANCED low-atomic segmented sum.
// 512 blocks x 4 waves; each wave owns 32 CONSECUTIVE sorted rows (~1.25
// code-runs avg). Rows staged 8-deep in registers, register accumulate,
// flush on code-change via 4 scalar atomicAdds/lane. No tail skew.
// dw must be zeroed beforehand.
// ---------------------------------------------------------------------------
__global__ __launch_bounds__(256) void dw_sum(const float* __restrict__ x,
                                              const int* __restrict__ perm,
                                              float* __restrict__ dw) {
  __shared__ int sp[128];
  const int tid = threadIdx.x;
  if (tid < 128) sp[tid] = perm[blockIdx.x * 128 + tid];
  __syncthreads();
  const int w = tid >> 6;
  const int l = tid & 63;
  const int* wp = sp + w * 32;

  float4 acc = make_float4(0.0f, 0.0f, 0.0f, 0.0f);
  int kcur = wp[0] >> 16;

  #pragma unroll
  for (int c = 0; c < 4; c++) {
    float4 v[8];
    int kk[8];
    #pragma unroll
    for (int j = 0; j < 8; j++) {
      const int p = wp[c * 8 + j];
      kk[j] = p >> 16;
      v[j] = *(const float4*)(x + (long)(p & 0xFFFF) * DD + l * 4);
    }
    #pragma unroll
    for (int j = 0; j < 8; j++) {
      if (kk[j] != kcur) {
        float* drow = dw + kcur * DD + l * 4;
        atomicAdd(drow + 0, acc.x);
        atomicAdd(drow + 1, acc.y);
        atomicAdd(drow + 2, acc.z);
        atomicAdd(drow + 3, acc.w);
        acc = make_float4(0.0f, 0.0f, 0.0f, 0.0f);
        kcur = kk[j];
      }
      acc.x += v[j].x; acc.y += v[j].y;
      acc.z += v[j].z; acc.w += v[j].w;
    }
  }
  {
    float* drow = dw + kcur * DD + l * 4;
    atomicAdd(drow + 0, acc.x);
    atomicAdd(drow + 1, acc.y);
    atomicAdd(drow + 2, acc.z);
    atomicAdd(drow + 3, acc.w);
  }
}

// ---------------------------------------------------------------------------
// Kernel 5: new_ema_w and new_embedding.
// ---------------------------------------------------------------------------
__global__ __launch_bounds__(256) void finalize2(
    const float* __restrict__ ema_w, const float* __restrict__ dw,
    const float* __restrict__ norm, float* __restrict__ outEmb,
    float* __restrict__ outW) {
  const int i = blockIdx.x * 256 + threadIdx.x;  // 0..262143
  const float nw = DECAY_F * ema_w[i] + OMD_F * dw[i];
  outW[i] = nw;
  outEmb[i] = nw / norm[i >> 8];
}

// ---------------------------------------------------------------------------
extern "C" void kernel_launch(void* const* d_in, const int* in_sizes, int n_in,
                              void* d_out, int out_size, void* d_ws, size_t ws_size,
                              hipStream_t stream) {
  const float* x = (const float*)d_in[0];        // [65536, 256]
  const float* emb = (const float*)d_in[1];      // [1024, 256]
  const float* ema_cs = (const float*)d_in[2];   // [1024]
  const float* ema_w = (const float*)d_in[3];    // [1024, 256]
  float* out = (float*)d_out;
  float* ws = (float*)d_ws;

  // --- workspace (float offsets) ---
  float* eSq = ws + 0;                   // 1024
  float* sseSlots = ws + 1024;           // 256   (zeroed by prep_all)
  int* cntI = (int*)(ws + 1280);         // 1024 ints (zeroed by prep_all)
  float* dw = ws + 2304;                 // 262144 (zeroed by prep_all)
  float* norm = ws + 264448;             // 1024
  int* starts = (int*)(ws + 265472);     // 1024 ints
  int* cursor = (int*)(ws + 266496);     // 1024 ints
  int* idxFinal = (int*)(ws + 267520);   // 65536 ints
  int* perm = (int*)(ws + 333056);       // 65536 ints (packed (k<<16)|n)

  // --- d_out doubles as phase-1 scratch (stream-ordered lifetimes) ---
  short* xhi = (short*)out;                     // out[0..8388608)
  short* xlo = (short*)(out + 8388608);         // out[8388608..16777216)
  short* eT = (short*)(out + 16777216);         // 524288 shorts
  int2* cand = (int2*)(out + 17039360);         // 65536 int2

  // --- final output layout (return-order flat, fp32) ---
  float* outQ = out;                    // 16777216  quantized_st
  float* outCodes = out + 16777216;     // 65536     codes (as float)
  float* outLoss = out + 16842752;      // 2         commitment, codebook
  float* outEmb = out + 16842754;       // 262144    new_embedding
  float* outCS = out + 17104898;        // 1024      new_cluster_size
  float* outW = out + 17105922;         // 262144    new_ema_w

  prep_all<<<8738, 256, 0, stream>>>(x, emb, xhi, xlo, eT, eSq, ws + 1024);
  argmin_mfma<<<NV / 128, 256, 0, stream>>>(xhi, xlo, eT, eSq, cand);
  gather_rescue<<<NV / 4, 256, 0, stream>>>(x, emb, cand, outQ, outCodes,
                                            idxFinal, sseSlots, cntI);
  scan_fin<<<1, 1024, 0, stream>>>(cntI, ema_cs, sseSlots, starts, cursor,
                                   norm, outCS, outLoss);
  scatter_kernel<<<NV / 256, 256, 0, stream>>>(idxFinal, cursor, perm);
  dw_sum<<<NV / 128, 256, 0, stream>>>(x, perm, dw);
  finalize2<<<KN * DD / 256, 256, 0, stream>>>(ema_w, dw, norm, outEmb, outW);
}